// Round 3
// baseline (193.237 us; speedup 1.0000x reference)
//
#include <hip/hip_runtime.h>
#include <math.h>

#define NGRAPH 256
#define HEADS  8
#define DIN    512
#define EPG    256   // edges per graph
#define NEDGE  65536

typedef short bf16x8 __attribute__((ext_vector_type(8)));
typedef float f32x4 __attribute__((ext_vector_type(4)));

__device__ __forceinline__ float softplusf(float v) {
    return (v > 20.f) ? v : log1pf(expf(v));
}
__device__ __forceinline__ unsigned short f2bf(float f) {   // RNE f32 -> bf16
    union { float f; unsigned u; } c; c.f = f;
    unsigned r = c.u + 0x7fffu + ((c.u >> 16) & 1u);
    return (unsigned short)(r >> 16);
}
__device__ __forceinline__ float bf2f(unsigned short h) {
    union { float f; unsigned u; } c; c.u = ((unsigned)h) << 16;
    return c.f;
}
// XOR-swizzled element index into a [64][64] bf16 LDS tile (16B-group granularity).
__device__ __forceinline__ int swz_idx(int row, int t) {
    int g = ((t >> 3) ^ (row ^ (row >> 3))) & 7;
    return (row << 6) | (g << 3) | (t & 7);
}
// Load 8 consecutive f32, split into bf16 hi + bf16 lo (truncation + residual).
__device__ __forceinline__ void loadsplit(const float* p, bf16x8& hi, bf16x8& lo) {
    float4 u = *(const float4*)p;
    float4 v = *(const float4*)(p + 4);
    float vv[8] = {u.x, u.y, u.z, u.w, v.x, v.y, v.z, v.w};
    #pragma unroll
    for (int j = 0; j < 8; ++j) {
        union { float f; unsigned q; } c; c.f = vv[j];
        unsigned hb = c.q & 0xffff0000u;
        hi[j] = (short)(unsigned short)(hb >> 16);
        union { float f; unsigned q; } d; d.q = hb;
        union { float f; unsigned q; } e2; e2.f = vv[j] - d.f;
        lo[j] = (short)(unsigned short)(e2.q >> 16);
    }
}

// ---------------- K1: CB = C·B^T per graph, pre-summed bf16 output (2 MB total).
// Grid (NGRAPH, 4): block (b, qy) computes 32x32 tile at (32*(qy>>1), 32*(qy&1)).
// 4 waves: wave w -> 16x16 sub-tile (mi = (w>>1), ni = (w&1)).
__global__ __launch_bounds__(256, 4) void cb_bf16_kernel(const float* __restrict__ Bm,
                                                         const float* __restrict__ Cm,
                                                         unsigned short* __restrict__ CBbf) {
    const int b = blockIdx.x;
    const int qi = blockIdx.y >> 1;       // row quadrant (0..1)
    const int qj = blockIdx.y & 1;        // col quadrant (0..1)
    const int tid = threadIdx.x;
    const int w = tid >> 6;
    const int lane = tid & 63;
    const int lm = lane & 15;
    const int quad = lane >> 4;
    const int mi = qi * 2 + (w >> 1);     // 16-row tile index (0..3)
    const int ni = qj * 2 + (w & 1);      // 16-col tile index (0..3)

    const float* Cr = Cm + ((size_t)(b * 64 + mi * 16 + lm)) * DIN + quad * 8;
    const float* Br = Bm + ((size_t)(b * 64 + ni * 16 + lm)) * DIN + quad * 8;
    f32x4 acc = {0.f, 0.f, 0.f, 0.f};
    #pragma unroll 4
    for (int ks = 0; ks < 16; ++ks) {
        bf16x8 ah, al, bh, bl;
        loadsplit(Cr + ks * 32, ah, al);
        loadsplit(Br + ks * 32, bh, bl);
        acc = __builtin_amdgcn_mfma_f32_16x16x32_bf16(ah, bh, acc, 0, 0, 0);
        acc = __builtin_amdgcn_mfma_f32_16x16x32_bf16(ah, bl, acc, 0, 0, 0);
        acc = __builtin_amdgcn_mfma_f32_16x16x32_bf16(al, bh, acc, 0, 0, 0);
    }
    // C/D layout: col = lane&15, row = quad*4 + r
    unsigned short* o = CBbf + (size_t)b * 4096;
    #pragma unroll
    for (int r = 0; r < 4; ++r)
        o[(mi * 16 + quad * 4 + r) * 64 + ni * 16 + lm] = f2bf(acc[r]);
}

// ---------------- K2: per-(graph,head) band build + solve + MFMA GEMM.
// Grid (NGRAPH, HEADS), 256 threads = 4 waves. LDS ~27 KB -> 4-5 blocks/CU.
__global__ __launch_bounds__(256, 4) void dag_head_kernel(
        const float* __restrict__ x,
        const float* __restrict__ dt,
        const float* __restrict__ dt_edge,
        const float* __restrict__ dt_bias,
        const float* __restrict__ Dp,
        const float* __restrict__ dag_masks,
        const int* __restrict__ edge_index,
        const unsigned short* __restrict__ CBbf,
        float* __restrict__ out) {
    __shared__ __align__(16) unsigned short CBsh[4096];  // CB[i][t] bf16, linear
    __shared__ __align__(16) unsigned short Xt[4096];    // X^T[e][t] bf16, swizzled
    __shared__ __align__(16) unsigned short Wl[4096];    // W[i][t]  bf16, swizzled
    __shared__ float Ab[448];                            // band [i][d-1], d in 1..7
    __shared__ float dts[64];
    __shared__ float dtt[64];
    __shared__ float dnsh[64];
    __shared__ float ecsh[64];

    const int b = blockIdx.x;
    const int head = blockIdx.y;
    const int tid = threadIdx.x;
    const int w = tid >> 6;
    const int lane = tid & 63;
    const int lm = lane & 15;
    const int quad = lane >> 4;
    const float bias = dt_bias[head];

    // ---- stage CB (8 KB, coalesced 16B loads) ----
    {
        const float4* src = (const float4*)(CBbf + (size_t)b * 4096);
        float4* dst = (float4*)CBsh;
        dst[tid] = src[tid];
        dst[256 + tid] = src[256 + tid];
    }
    // ---- zero + node softplus ----
    if (tid < 64) {
        float2 dv = *(const float2*)(dt + ((size_t)(b * 64 + tid)) * 16 + head * 2);
        dts[tid] = softplusf(dv.x + bias);
        dtt[tid] = softplusf(dv.y + bias);
        dnsh[tid] = 0.f;
        ecsh[tid] = 0.f;
    }
    for (int k = tid; k < 448; k += 256) Ab[k] = 0.f;
    // ---- stage X^T tile (swizzled bf16): wave w covers t rows [16w,16w+16) ----
    {
        const float* xg = x + (size_t)b * 64 * DIN + head * 64;
        #pragma unroll
        for (int rr = 0; rr < 4; ++rr) {
            int t = w * 16 + rr * 4 + quad;
            int e0 = lm * 4;
            float4 v = *(const float4*)(xg + (size_t)t * DIN + e0);
            Xt[swz_idx(e0 + 0, t)] = f2bf(v.x);
            Xt[swz_idx(e0 + 1, t)] = f2bf(v.y);
            Xt[swz_idx(e0 + 2, t)] = f2bf(v.z);
            Xt[swz_idx(e0 + 3, t)] = f2bf(v.w);
        }
    }
    __syncthreads();

    // ---- edge scatter (1 edge/thread) ----
    {
        int e = b * EPG + tid;
        int sl = edge_index[e] & 63;
        int dl = edge_index[NEDGE + e] & 63;
        float mk = dag_masks[e];
        float de = softplusf(dt_edge[(size_t)e * HEADS + head] + bias);
        float dsum = (dts[sl] + dtt[dl] + de) * 0.57735026918962576451f; // 1/sqrt(3)
        float dexp = expf(-dsum);
        atomicAdd(&Ab[dl * 7 + (dl - sl - 1)], dexp * mk);   // dl-sl in [1,7]
        atomicAdd(&dnsh[dl], dsum * mk);
        atomicAdd(&ecsh[dl], mk);
    }
    __syncthreads();

    // ---- band normalize (lane i = row i) ----
    if (tid < 64) {
        float eci = ecsh[tid];
        #pragma unroll
        for (int s = 0; s < 7; ++s) {
            int src = tid - 1 - s;
            if (src >= 0) {
                float den = sqrtf(eci * ecsh[src]);
                if (den < 1.f) den = 1.f;
                Ab[tid * 7 + s] = Ab[tid * 7 + s] / den;
            }
        }
    }
    __syncthreads();

    // ---- banded forward solve (wave 0; lane j = column j) ----
    if (w == 0) {
        const int j = lane;
        const float Dh = Dp[head];
        float mwin[7] = {0.f, 0.f, 0.f, 0.f, 0.f, 0.f, 0.f};
        for (int i = 0; i < 64; ++i) {
            float mi_ = (j == i) ? 1.f : 0.f;
            #pragma unroll
            for (int s = 0; s < 7; ++s) mi_ += Ab[i * 7 + s] * mwin[s];
            float wv = mi_ * bf2f(CBsh[i * 64 + j]) * dnsh[i];
            if (j == i) wv += Dh;
            Wl[swz_idx(i, j)] = f2bf(wv);   // i uniform -> conflict-free store
            #pragma unroll
            for (int s = 6; s > 0; --s) mwin[s] = mwin[s - 1];
            mwin[0] = mi_;
        }
    }
    __syncthreads();

    // ---- y = W·X via mfma_f32_16x16x32_bf16; wave w -> output rows [16w,16w+16) ----
    {
        bf16x8 a0 = *(const bf16x8*)(&Wl[swz_idx(16 * w + lm, quad * 8)]);
        bf16x8 a1 = *(const bf16x8*)(&Wl[swz_idx(16 * w + lm, 32 + quad * 8)]);
        float* og = out + (size_t)b * 64 * DIN + head * 64;
        #pragma unroll
        for (int eb = 0; eb < 4; ++eb) {
            int er = eb * 16 + lm;
            bf16x8 b0 = *(const bf16x8*)(&Xt[swz_idx(er, quad * 8)]);
            bf16x8 b1 = *(const bf16x8*)(&Xt[swz_idx(er, 32 + quad * 8)]);
            f32x4 acc = {0.f, 0.f, 0.f, 0.f};
            acc = __builtin_amdgcn_mfma_f32_16x16x32_bf16(a0, b0, acc, 0, 0, 0);
            acc = __builtin_amdgcn_mfma_f32_16x16x32_bf16(a1, b1, acc, 0, 0, 0);
            #pragma unroll
            for (int r = 0; r < 4; ++r) {
                int row = 16 * w + quad * 4 + r;
                og[(size_t)row * DIN + eb * 16 + lm] = acc[r];
            }
        }
    }
}

// ---------------- Fallback: round-1 single fused kernel (used only if ws too small).
__global__ __launch_bounds__(512, 2) void dag_fused_kernel(
        const float* __restrict__ x,
        const float* __restrict__ Bm,
        const float* __restrict__ Cm,
        const float* __restrict__ dt,
        const float* __restrict__ dt_edge,
        const float* __restrict__ dt_bias,
        const float* __restrict__ Dp,
        const float* __restrict__ dag_masks,
        const int* __restrict__ edge_index,
        float* __restrict__ out) {
    __shared__ unsigned short CBsh[64 * 68];
    __shared__ __align__(16) unsigned short Xt[HEADS][4096];
    __shared__ __align__(16) unsigned short Wl[HEADS][4096];
    __shared__ float Ab[HEADS][448];
    __shared__ float dts[HEADS][64];
    __shared__ float dtt[HEADS][64];
    __shared__ float dnsh[HEADS][64];
    __shared__ float ecsh[64];

    const int b = blockIdx.x;
    const int tid = threadIdx.x;
    const int w = tid >> 6;
    const int lane = tid & 63;
    const int lm = lane & 15;
    const int quad = lane >> 4;
    const float bias = dt_bias[w];

    {
        float2 dv = *(const float2*)(dt + ((size_t)(b * 64 + lane)) * 16 + w * 2);
        dts[w][lane] = softplusf(dv.x + bias);
        dtt[w][lane] = softplusf(dv.y + bias);
        dnsh[w][lane] = 0.f;
        #pragma unroll
        for (int s = 0; s < 7; ++s) Ab[w][lane * 7 + s] = 0.f;
        if (w == 0) ecsh[lane] = 0.f;
    }
    __syncthreads();

    if (tid < EPG) {
        int e = b * EPG + tid;
        atomicAdd(&ecsh[edge_index[NEDGE + e] & 63], dag_masks[e]);
    }
    {
        const int mi = w >> 1;
        const int ni0 = (w & 1) * 2;
        const float* Cr = Cm + ((size_t)(b * 64 + mi * 16 + lm)) * DIN + quad * 8;
        const float* B0 = Bm + ((size_t)(b * 64 + ni0 * 16 + lm)) * DIN + quad * 8;
        const float* B1 = B0 + (size_t)16 * DIN;
        f32x4 acc0 = {0.f, 0.f, 0.f, 0.f};
        f32x4 acc1 = {0.f, 0.f, 0.f, 0.f};
        #pragma unroll 4
        for (int ks = 0; ks < 16; ++ks) {
            bf16x8 ah, al, b0h, b0l, b1h, b1l;
            loadsplit(Cr + ks * 32, ah, al);
            loadsplit(B0 + ks * 32, b0h, b0l);
            loadsplit(B1 + ks * 32, b1h, b1l);
            acc0 = __builtin_amdgcn_mfma_f32_16x16x32_bf16(ah, b0h, acc0, 0, 0, 0);
            acc0 = __builtin_amdgcn_mfma_f32_16x16x32_bf16(ah, b0l, acc0, 0, 0, 0);
            acc0 = __builtin_amdgcn_mfma_f32_16x16x32_bf16(al, b0h, acc0, 0, 0, 0);
            acc1 = __builtin_amdgcn_mfma_f32_16x16x32_bf16(ah, b1h, acc1, 0, 0, 0);
            acc1 = __builtin_amdgcn_mfma_f32_16x16x32_bf16(ah, b1l, acc1, 0, 0, 0);
            acc1 = __builtin_amdgcn_mfma_f32_16x16x32_bf16(al, b1h, acc1, 0, 0, 0);
        }
        #pragma unroll
        for (int r = 0; r < 4; ++r) {
            int row = mi * 16 + quad * 4 + r;
            CBsh[row * 68 + ni0 * 16 + lm] = f2bf(acc0[r]);
            CBsh[row * 68 + (ni0 + 1) * 16 + lm] = f2bf(acc1[r]);
        }
    }
    {
        const float* xg = x + (size_t)b * 64 * DIN + w * 64;
        #pragma unroll 4
        for (int r = 0; r < 16; ++r) {
            int t = r * 4 + quad;
            int e0 = lm * 4;
            float4 v = *(const float4*)(xg + (size_t)t * DIN + e0);
            Xt[w][swz_idx(e0 + 0, t)] = f2bf(v.x);
            Xt[w][swz_idx(e0 + 1, t)] = f2bf(v.y);
            Xt[w][swz_idx(e0 + 2, t)] = f2bf(v.z);
            Xt[w][swz_idx(e0 + 3, t)] = f2bf(v.w);
        }
    }
    __syncthreads();

    {
        #pragma unroll
        for (int eo = 0; eo < 4; ++eo) {
            int e = b * EPG + eo * 64 + lane;
            int sl = edge_index[e] & 63;
            int dl = edge_index[NEDGE + e] & 63;
            float mk = dag_masks[e];
            float de = softplusf(dt_edge[(size_t)e * HEADS + w] + bias);
            float dsum = (dts[w][sl] + dtt[w][dl] + de) * 0.57735026918962576451f;
            float dexp = expf(-dsum);
            atomicAdd(&Ab[w][dl * 7 + (dl - sl - 1)], dexp * mk);
            atomicAdd(&dnsh[w][dl], dsum * mk);
        }
    }
    __syncthreads();

    {
        float eci = ecsh[lane];
        #pragma unroll
        for (int s = 0; s < 7; ++s) {
            int src = lane - 1 - s;
            if (src >= 0) {
                float den = sqrtf(eci * ecsh[src]);
                if (den < 1.f) den = 1.f;
                Ab[w][lane * 7 + s] = Ab[w][lane * 7 + s] / den;
            }
        }
    }
    __syncthreads();

    {
        const int j = lane;
        const float Dh = Dp[w];
        float mwin[7] = {0.f, 0.f, 0.f, 0.f, 0.f, 0.f, 0.f};
        const float* abp = &Ab[w][0];
        for (int i = 0; i < 64; ++i) {
            float mi_ = (j == i) ? 1.f : 0.f;
            #pragma unroll
            for (int s = 0; s < 7; ++s) mi_ += abp[i * 7 + s] * mwin[s];
            float wv = mi_ * bf2f(CBsh[i * 68 + j]) * dnsh[w][i];
            if (j == i) wv += Dh;
            Wl[w][swz_idx(i, j)] = f2bf(wv);
            #pragma unroll
            for (int s = 6; s > 0; --s) mwin[s] = mwin[s - 1];
            mwin[0] = mi_;
        }
    }
    __syncthreads();

    {
        bf16x8 af[4][2];
        #pragma unroll
        for (int mi = 0; mi < 4; ++mi) {
            int row0 = mi * 16 + lm;
            af[mi][0] = *(const bf16x8*)(&Wl[w][swz_idx(row0, quad * 8)]);
            af[mi][1] = *(const bf16x8*)(&Wl[w][swz_idx(row0, 32 + quad * 8)]);
        }
        float* og = out + (size_t)b * 64 * DIN + w * 64;
        #pragma unroll
        for (int eb = 0; eb < 4; ++eb) {
            int er = eb * 16 + lm;
            bf16x8 b0 = *(const bf16x8*)(&Xt[w][swz_idx(er, quad * 8)]);
            bf16x8 b1 = *(const bf16x8*)(&Xt[w][swz_idx(er, 32 + quad * 8)]);
            #pragma unroll
            for (int mi = 0; mi < 4; ++mi) {
                f32x4 acc = {0.f, 0.f, 0.f, 0.f};
                acc = __builtin_amdgcn_mfma_f32_16x16x32_bf16(af[mi][0], b0, acc, 0, 0, 0);
                acc = __builtin_amdgcn_mfma_f32_16x16x32_bf16(af[mi][1], b1, acc, 0, 0, 0);
                #pragma unroll
                for (int r = 0; r < 4; ++r) {
                    int row = mi * 16 + quad * 4 + r;
                    og[(size_t)row * DIN + eb * 16 + lm] = acc[r];
                }
            }
        }
    }
}

extern "C" void kernel_launch(void* const* d_in, const int* in_sizes, int n_in,
                              void* d_out, int out_size, void* d_ws, size_t ws_size,
                              hipStream_t stream) {
    (void)in_sizes; (void)n_in; (void)out_size;
    const float* x        = (const float*)d_in[0];
    const float* Bm       = (const float*)d_in[1];
    const float* Cm       = (const float*)d_in[2];
    const float* dt       = (const float*)d_in[3];
    const float* dt_edge  = (const float*)d_in[4];
    const float* dt_bias  = (const float*)d_in[5];
    const float* Dp       = (const float*)d_in[6];
    const float* dag_mask = (const float*)d_in[7];
    const int*   edge_idx = (const int*)d_in[8];
    float* out = (float*)d_out;

    const size_t CB_BYTES = (size_t)NGRAPH * 4096 * sizeof(unsigned short);  // 2 MiB

    if (ws_size >= CB_BYTES) {
        unsigned short* CBbf = (unsigned short*)d_ws;
        cb_bf16_kernel<<<dim3(NGRAPH, 4), 256, 0, stream>>>(Bm, Cm, CBbf);
        dag_head_kernel<<<dim3(NGRAPH, HEADS), 256, 0, stream>>>(
            x, dt, dt_edge, dt_bias, Dp, dag_mask, edge_idx, CBbf, out);
    } else {
        dag_fused_kernel<<<dim3(NGRAPH), dim3(512), 0, stream>>>(
            x, Bm, Cm, dt, dt_edge, dt_bias, Dp, dag_mask, edge_idx, out);
    }
}

// Round 4
// 165.842 us; speedup vs baseline: 1.1652x; 1.1652x over previous
//
#include <hip/hip_runtime.h>
#include <math.h>

#define NGRAPH 256
#define HEADS  8
#define DIN    512
#define EPG    256   // edges per graph
#define NEDGE  65536
#define LOG2E 1.44269504088896341f
#define LN2   0.69314718055994531f

typedef short bf16x8 __attribute__((ext_vector_type(8)));
typedef float f32x4 __attribute__((ext_vector_type(4)));

// fast softplus on HW-native base-2 ops (v_exp_f32 / v_log_f32)
__device__ __forceinline__ float softplusf(float v) {
    if (v > 20.f) return v;
    float t = exp2f(v * LOG2E);
    return LN2 * log2f(1.f + t);
}
__device__ __forceinline__ unsigned short f2bf(float f) {   // RNE f32 -> bf16
    union { float f; unsigned u; } c; c.f = f;
    unsigned r = c.u + 0x7fffu + ((c.u >> 16) & 1u);
    return (unsigned short)(r >> 16);
}
__device__ __forceinline__ float bf2f(unsigned short h) {
    union { float f; unsigned u; } c; c.u = ((unsigned)h) << 16;
    return c.f;
}
// XOR-swizzled element index into a [64][64] bf16 LDS tile (16B-group granularity).
__device__ __forceinline__ int swz_idx(int row, int t) {
    int g = ((t >> 3) ^ (row ^ (row >> 3))) & 7;
    return (row << 6) | (g << 3) | (t & 7);
}
// Load 8 consecutive f32, split into bf16 hi + bf16 lo (truncation + residual).
__device__ __forceinline__ void loadsplit(const float* p, bf16x8& hi, bf16x8& lo) {
    float4 u = *(const float4*)p;
    float4 v = *(const float4*)(p + 4);
    float vv[8] = {u.x, u.y, u.z, u.w, v.x, v.y, v.z, v.w};
    #pragma unroll
    for (int j = 0; j < 8; ++j) {
        union { float f; unsigned q; } c; c.f = vv[j];
        unsigned hb = c.q & 0xffff0000u;
        hi[j] = (short)(unsigned short)(hb >> 16);
        union { float f; unsigned q; } d; d.q = hb;
        union { float f; unsigned q; } e2; e2.f = vv[j] - d.f;
        lo[j] = (short)(unsigned short)(e2.q >> 16);
    }
}

// One block per graph, 512 threads = 8 waves, wave w owns head w end-to-end.
// ONE barrier total (for cross-wave CBsh + ecsh); every other phase is wave-private
// and relies on intra-wave in-order LDS (wave64 lockstep).
__global__ __launch_bounds__(512, 2) void dag_fused_v2(
        const float* __restrict__ x,
        const float* __restrict__ Bm,
        const float* __restrict__ Cm,
        const float* __restrict__ dt,
        const float* __restrict__ dt_edge,
        const float* __restrict__ dt_bias,
        const float* __restrict__ Dp,
        const float* __restrict__ dag_masks,
        const int* __restrict__ edge_index,
        float* __restrict__ out) {
    __shared__ unsigned short CBsh[64 * 68];                   // CB[i][t] bf16 (cross-wave)
    __shared__ __align__(16) unsigned short Xt[HEADS][4096];   // X^T[e][t] bf16, swizzled
    __shared__ __align__(16) unsigned short Wl[HEADS][4096];   // W[i][t]  bf16, swizzled
    __shared__ float Ab[HEADS][448];                           // band [i][d-1], d in 1..7
    __shared__ float dts[HEADS][64];
    __shared__ float dtt[HEADS][64];
    __shared__ float dnsh[HEADS][64];
    __shared__ float ecsh[64];                                 // head-independent (wave 0)

    const int b = blockIdx.x;
    const int tid = threadIdx.x;
    const int w = tid >> 6;       // wave id == head id
    const int lane = tid & 63;
    const int lm = lane & 15;
    const int quad = lane >> 4;
    const float bias = dt_bias[w];

    // ---- phase 0 (wave-private): node softplus + zero own band ----
    {
        float2 dv = *(const float2*)(dt + ((size_t)(b * 64 + lane)) * 16 + w * 2);
        dts[w][lane] = softplusf(dv.x + bias);
        dtt[w][lane] = softplusf(dv.y + bias);
        dnsh[w][lane] = 0.f;
        #pragma unroll
        for (int s = 0; s < 7; ++s) Ab[w][lane * 7 + s] = 0.f;
        if (w == 0) ecsh[lane] = 0.f;
    }

    // ---- CB = C·B^T via split-bf16 MFMA (cross-wave output CBsh) ----
    {
        const int mi = w >> 1;
        const int ni0 = (w & 1) * 2;
        const float* Cr = Cm + ((size_t)(b * 64 + mi * 16 + lm)) * DIN + quad * 8;
        const float* B0 = Bm + ((size_t)(b * 64 + ni0 * 16 + lm)) * DIN + quad * 8;
        const float* B1 = B0 + (size_t)16 * DIN;
        f32x4 acc0 = {0.f, 0.f, 0.f, 0.f};
        f32x4 acc1 = {0.f, 0.f, 0.f, 0.f};
        #pragma unroll 4
        for (int ks = 0; ks < 16; ++ks) {
            bf16x8 ah, al, b0h, b0l, b1h, b1l;
            loadsplit(Cr + ks * 32, ah, al);
            loadsplit(B0 + ks * 32, b0h, b0l);
            loadsplit(B1 + ks * 32, b1h, b1l);
            acc0 = __builtin_amdgcn_mfma_f32_16x16x32_bf16(ah, b0h, acc0, 0, 0, 0);
            acc0 = __builtin_amdgcn_mfma_f32_16x16x32_bf16(ah, b0l, acc0, 0, 0, 0);
            acc0 = __builtin_amdgcn_mfma_f32_16x16x32_bf16(al, b0h, acc0, 0, 0, 0);
            acc1 = __builtin_amdgcn_mfma_f32_16x16x32_bf16(ah, b1h, acc1, 0, 0, 0);
            acc1 = __builtin_amdgcn_mfma_f32_16x16x32_bf16(ah, b1l, acc1, 0, 0, 0);
            acc1 = __builtin_amdgcn_mfma_f32_16x16x32_bf16(al, b1h, acc1, 0, 0, 0);
        }
        // C/D layout: col = lane&15, row = quad*4 + r
        #pragma unroll
        for (int r = 0; r < 4; ++r) {
            int row = mi * 16 + quad * 4 + r;
            CBsh[row * 68 + ni0 * 16 + lm] = f2bf(acc0[r]);
            CBsh[row * 68 + (ni0 + 1) * 16 + lm] = f2bf(acc1[r]);
        }
    }

    // ---- Xt stage (wave-private), packed ds_write_b64: 16 LDS ops/thread (was 64) ----
    {
        const float* xg = x + (size_t)b * 64 * DIN + w * 64;
        #pragma unroll
        for (int r = 0; r < 4; ++r) {
            int t0 = quad * 4 + r * 16;   // multiple of 4; {0,4,8,...,60}
            int e0 = lm * 4;
            float4 v0 = *(const float4*)(xg + (size_t)(t0 + 0) * DIN + e0);
            float4 v1 = *(const float4*)(xg + (size_t)(t0 + 1) * DIN + e0);
            float4 v2 = *(const float4*)(xg + (size_t)(t0 + 2) * DIN + e0);
            float4 v3 = *(const float4*)(xg + (size_t)(t0 + 3) * DIN + e0);
            float a0[4] = {v0.x, v0.y, v0.z, v0.w};
            float a1[4] = {v1.x, v1.y, v1.z, v1.w};
            float a2[4] = {v2.x, v2.y, v2.z, v2.w};
            float a3[4] = {v3.x, v3.y, v3.z, v3.w};
            #pragma unroll
            for (int k = 0; k < 4; ++k) {
                unsigned long long pk =
                      (unsigned long long)f2bf(a0[k])
                    | ((unsigned long long)f2bf(a1[k]) << 16)
                    | ((unsigned long long)f2bf(a2[k]) << 32)
                    | ((unsigned long long)f2bf(a3[k]) << 48);
                *(unsigned long long*)(&Xt[w][swz_idx(e0 + k, t0)]) = pk;
            }
        }
    }

    // ---- edge scatter (wave-private band; wave 0 also builds shared ecsh) ----
    {
        #pragma unroll
        for (int eo = 0; eo < 4; ++eo) {
            int e = b * EPG + eo * 64 + lane;
            int sl = edge_index[e] & 63;
            int dl = edge_index[NEDGE + e] & 63;
            float mk = dag_masks[e];
            float de = softplusf(dt_edge[(size_t)e * HEADS + w] + bias);
            float dsum = (dts[w][sl] + dtt[w][dl] + de) * 0.57735026918962576451f; // 1/sqrt(3)
            float dexp = exp2f(-dsum * LOG2E);
            atomicAdd(&Ab[w][dl * 7 + (dl - sl - 1)], dexp * mk);   // dl-sl in [1,7]
            atomicAdd(&dnsh[w][dl], dsum * mk);
            if (w == 0) atomicAdd(&ecsh[dl], mk);
        }
    }

    __syncthreads();   // the ONLY barrier: publishes CBsh (all waves) + ecsh (wave 0)

    // ---- band normalize (wave-private; lane i = row i of own head's band) ----
    {
        float eci = ecsh[lane];
        #pragma unroll
        for (int s = 0; s < 7; ++s) {
            int src = lane - 1 - s;
            if (src >= 0) {
                float p = eci * ecsh[src];
                float f = fminf(1.f, rsqrtf(p));   // = 1/max(1,sqrt(p)); p=0 -> 1
                Ab[w][lane * 7 + s] *= f;
            }
        }
    }

    // ---- banded forward solve (all 8 waves, own head; software-pipelined) ----
    // lane j = column j of M=(I-A)^-1; W[i][j] = M[i][j]*CB[i][j]*dn[i] (+D diag)
    {
        const int j = lane;
        const float Dh = Dp[w];
        float mwin[7] = {0.f, 0.f, 0.f, 0.f, 0.f, 0.f, 0.f};
        float cab[7];
        #pragma unroll
        for (int s = 0; s < 7; ++s) cab[s] = Ab[w][s];
        float cbv = bf2f(CBsh[j]);
        float dnv = dnsh[w][0];
        for (int i = 0; i < 64; ++i) {
            // prefetch row i+1 while computing row i (hides LDS latency)
            float nab[7], ncb = 0.f, ndn = 0.f;
            if (i < 63) {
                #pragma unroll
                for (int s = 0; s < 7; ++s) nab[s] = Ab[w][(i + 1) * 7 + s];
                ncb = bf2f(CBsh[(i + 1) * 68 + j]);
                ndn = dnsh[w][i + 1];
            } else {
                #pragma unroll
                for (int s = 0; s < 7; ++s) nab[s] = 0.f;
            }
            float diag = (j == i) ? 1.f : 0.f;
            // tree-summed recurrence (dependent chain ~3 FMA deep, not 7)
            float t0 = fmaf(cab[0], mwin[0], fmaf(cab[1], mwin[1], diag));
            float t1 = fmaf(cab[2], mwin[2], fmaf(cab[3], mwin[3], cab[4] * mwin[4]));
            float t2 = fmaf(cab[5], mwin[5], cab[6] * mwin[6]);
            float mi_ = t0 + (t1 + t2);
            float wv = mi_ * cbv * dnv;
            if (j == i) wv += Dh;
            Wl[w][swz_idx(i, j)] = f2bf(wv);   // i uniform -> conflict-free
            #pragma unroll
            for (int s = 6; s > 0; --s) mwin[s] = mwin[s - 1];
            mwin[0] = mi_;
            #pragma unroll
            for (int s = 0; s < 7; ++s) cab[s] = nab[s];
            cbv = ncb;
            dnv = ndn;
        }
    }

    // ---- y = W·X via mfma_f32_16x16x32_bf16 (wave-private; no barrier needed) ----
    {
        bf16x8 af[4][2];
        #pragma unroll
        for (int mi = 0; mi < 4; ++mi) {
            int row0 = mi * 16 + lm;
            af[mi][0] = *(const bf16x8*)(&Wl[w][swz_idx(row0, quad * 8)]);
            af[mi][1] = *(const bf16x8*)(&Wl[w][swz_idx(row0, 32 + quad * 8)]);
        }
        float* og = out + (size_t)b * 64 * DIN + w * 64;
        #pragma unroll
        for (int eb = 0; eb < 4; ++eb) {
            int er = eb * 16 + lm;
            bf16x8 b0 = *(const bf16x8*)(&Xt[w][swz_idx(er, quad * 8)]);
            bf16x8 b1 = *(const bf16x8*)(&Xt[w][swz_idx(er, 32 + quad * 8)]);
            #pragma unroll
            for (int mi = 0; mi < 4; ++mi) {
                f32x4 acc = {0.f, 0.f, 0.f, 0.f};
                acc = __builtin_amdgcn_mfma_f32_16x16x32_bf16(af[mi][0], b0, acc, 0, 0, 0);
                acc = __builtin_amdgcn_mfma_f32_16x16x32_bf16(af[mi][1], b1, acc, 0, 0, 0);
                #pragma unroll
                for (int r = 0; r < 4; ++r) {
                    int row = mi * 16 + quad * 4 + r;
                    og[(size_t)row * DIN + eb * 16 + lm] = acc[r];
                }
            }
        }
    }
}

extern "C" void kernel_launch(void* const* d_in, const int* in_sizes, int n_in,
                              void* d_out, int out_size, void* d_ws, size_t ws_size,
                              hipStream_t stream) {
    (void)in_sizes; (void)n_in; (void)out_size; (void)d_ws; (void)ws_size;
    dag_fused_v2<<<dim3(NGRAPH), dim3(512), 0, stream>>>(
        (const float*)d_in[0],   // x
        (const float*)d_in[1],   // B
        (const float*)d_in[2],   // C
        (const float*)d_in[3],   // dt
        (const float*)d_in[4],   // dt_edge
        (const float*)d_in[5],   // dt_bias
        (const float*)d_in[6],   // D
        (const float*)d_in[7],   // dag_masks
        (const int*)d_in[8],     // edge_index
        (float*)d_out);
}

// Round 5
// 163.647 us; speedup vs baseline: 1.1808x; 1.0134x over previous
//
#include <hip/hip_runtime.h>
#include <math.h>

#define NGRAPH 256
#define HEADS  8
#define DIN    512
#define EPG    256   // edges per graph
#define NEDGE  65536
#define LOG2E 1.44269504088896341f
#define LN2   0.69314718055994531f

typedef short bf16x8 __attribute__((ext_vector_type(8)));
typedef float f32x4 __attribute__((ext_vector_type(4)));

// fast softplus on HW-native base-2 ops (v_exp_f32 / v_log_f32)
__device__ __forceinline__ float softplusf(float v) {
    if (v > 20.f) return v;
    float t = exp2f(v * LOG2E);
    return LN2 * log2f(1.f + t);
}
__device__ __forceinline__ unsigned short f2bf(float f) {   // RNE f32 -> bf16
    union { float f; unsigned u; } c; c.f = f;
    unsigned r = c.u + 0x7fffu + ((c.u >> 16) & 1u);
    return (unsigned short)(r >> 16);
}
__device__ __forceinline__ float bf2f(unsigned short h) {
    union { float f; unsigned u; } c; c.u = ((unsigned)h) << 16;
    return c.f;
}
// XOR-swizzled element index into a [64][64] bf16 LDS tile (16B-group granularity).
// b128 fragment reads across 16 rows land on distinct 16B slots -> <=2-way (free).
__device__ __forceinline__ int swz_idx(int row, int t) {
    int g = ((t >> 3) ^ (row ^ (row >> 3))) & 7;
    return (row << 6) | (g << 3) | (t & 7);
}
// split f32 -> bf16 hi (truncation) + bf16 lo (truncation of residual)
__device__ __forceinline__ void split1(float f, unsigned short& hi, unsigned short& lo) {
    union { float f; unsigned q; } c; c.f = f;
    unsigned hb = c.q & 0xffff0000u;
    hi = (unsigned short)(hb >> 16);
    union { float f; unsigned q; } d; d.q = hb;
    union { float f; unsigned q; } e2; e2.f = f - d.f;
    lo = (unsigned short)(e2.q >> 16);
}

// Cooperative stage of one 64-col k-chunk of C and B into split-bf16 LDS tiles.
// buf layout (ush units): Chi=0, Clo=4096, Bhi=8192, Blo=12288 (each a swizzled [64][64] tile)
__device__ __forceinline__ void stage_chunk(int c, unsigned short* buf,
                                            const float* __restrict__ Cm,
                                            const float* __restrict__ Bm,
                                            int b, int tid) {
    #pragma unroll
    for (int i = 0; i < 4; ++i) {
        int u = tid * 4 + i;            // 2048 float4-units: [mat][row][col4-group]
        int mat = u >> 10;              // wave-uniform: waves 0-3 -> C, 4-7 -> B
        int rem = u & 1023;
        int row = rem >> 4;
        int col4 = (rem & 15) << 2;
        const float* src = (mat ? Bm : Cm) + ((size_t)(b * 64 + row)) * DIN + c * 64 + col4;
        float4 v = *(const float4*)src;
        float a[4] = {v.x, v.y, v.z, v.w};
        unsigned long long hp = 0, lp = 0;
        #pragma unroll
        for (int k = 0; k < 4; ++k) {
            unsigned short h, l;
            split1(a[k], h, l);
            hp |= ((unsigned long long)h) << (16 * k);
            lp |= ((unsigned long long)l) << (16 * k);
        }
        int idx = swz_idx(row, col4);   // col4 % 8 in {0,4}: 8B-aligned within 16B group
        unsigned short* thi = buf + (mat ? 8192 : 0);
        *(unsigned long long*)(thi + idx) = hp;
        *(unsigned long long*)(thi + 4096 + idx) = lp;
    }
}

// One block per graph, 512 threads = 8 waves, wave w owns head w end-to-end.
// CB operands staged ONCE per block via ping-pong LDS (unioned with Wl space).
__global__ __launch_bounds__(512, 2) void dag_fused_v3(
        const float* __restrict__ x,
        const float* __restrict__ Bm,
        const float* __restrict__ Cm,
        const float* __restrict__ dt,
        const float* __restrict__ dt_edge,
        const float* __restrict__ dt_bias,
        const float* __restrict__ Dp,
        const float* __restrict__ dag_masks,
        const int* __restrict__ edge_index,
        float* __restrict__ out) {
    // WS: CB-phase ping-pong stage buffers (2 x 32KB); after CB phase -> Wl[8][4096]
    __shared__ __align__(16) unsigned short WS[32768];         // 64 KB
    __shared__ __align__(16) unsigned short Xt[HEADS][4096];   // X^T[e][t] bf16, swizzled, 64 KB
    __shared__ __align__(16) unsigned short CBsh[4096];        // CB[i][t] bf16, 8 KB
    __shared__ float Ab[HEADS][448];                           // band [i][d-1], d in 1..7
    __shared__ float dts[HEADS][64];
    __shared__ float dtt[HEADS][64];
    __shared__ float dnsh[HEADS][64];
    __shared__ float ecsh[64];                                 // head-independent (wave 0)

    const int b = blockIdx.x;
    const int tid = threadIdx.x;
    const int w = tid >> 6;       // wave id == head id
    const int lane = tid & 63;
    const int lm = lane & 15;
    const int quad = lane >> 4;
    const float bias = dt_bias[w];

    // ---- phase 0 (wave-private): node softplus + zero own band ----
    {
        float2 dv = *(const float2*)(dt + ((size_t)(b * 64 + lane)) * 16 + w * 2);
        dts[w][lane] = softplusf(dv.x + bias);
        dtt[w][lane] = softplusf(dv.y + bias);
        dnsh[w][lane] = 0.f;
        #pragma unroll
        for (int s = 0; s < 7; ++s) Ab[w][lane * 7 + s] = 0.f;
        if (w == 0) ecsh[lane] = 0.f;
    }

    // ---- edge scatter (wave-private band; wave 0 also builds shared ecsh) ----
    // placed early so its global loads overlap the CB pipeline below
    {
        #pragma unroll
        for (int eo = 0; eo < 4; ++eo) {
            int e = b * EPG + eo * 64 + lane;
            int sl = edge_index[e] & 63;
            int dl = edge_index[NEDGE + e] & 63;
            float mk = dag_masks[e];
            float de = softplusf(dt_edge[(size_t)e * HEADS + w] + bias);
            float dsum = (dts[w][sl] + dtt[w][dl] + de) * 0.57735026918962576451f; // 1/sqrt(3)
            float dexp = exp2f(-dsum * LOG2E);
            atomicAdd(&Ab[w][dl * 7 + (dl - sl - 1)], dexp * mk);   // dl-sl in [1,7]
            atomicAdd(&dnsh[w][dl], dsum * mk);
            if (w == 0) atomicAdd(&ecsh[dl], mk);
        }
    }

    // ---- Xt stage (wave-private), packed ds_write_b64 ----
    {
        const float* xg = x + (size_t)b * 64 * DIN + w * 64;
        #pragma unroll
        for (int r = 0; r < 4; ++r) {
            int t0 = quad * 4 + r * 16;   // multiple of 4
            int e0 = lm * 4;
            float4 v0 = *(const float4*)(xg + (size_t)(t0 + 0) * DIN + e0);
            float4 v1 = *(const float4*)(xg + (size_t)(t0 + 1) * DIN + e0);
            float4 v2 = *(const float4*)(xg + (size_t)(t0 + 2) * DIN + e0);
            float4 v3 = *(const float4*)(xg + (size_t)(t0 + 3) * DIN + e0);
            float a0[4] = {v0.x, v0.y, v0.z, v0.w};
            float a1[4] = {v1.x, v1.y, v1.z, v1.w};
            float a2[4] = {v2.x, v2.y, v2.z, v2.w};
            float a3[4] = {v3.x, v3.y, v3.z, v3.w};
            #pragma unroll
            for (int k = 0; k < 4; ++k) {
                unsigned long long pk =
                      (unsigned long long)f2bf(a0[k])
                    | ((unsigned long long)f2bf(a1[k]) << 16)
                    | ((unsigned long long)f2bf(a2[k]) << 32)
                    | ((unsigned long long)f2bf(a3[k]) << 48);
                *(unsigned long long*)(&Xt[w][swz_idx(e0 + k, t0)]) = pk;
            }
        }
    }

    // ---- CB = C·B^T via split-bf16 MFMA, operands staged ONCE (ping-pong LDS) ----
    const int mi = w >> 1;
    const int ni0 = (w & 1) * 2;
    f32x4 acc0 = {0.f, 0.f, 0.f, 0.f};
    f32x4 acc1 = {0.f, 0.f, 0.f, 0.f};
    stage_chunk(0, WS, Cm, Bm, b, tid);
    for (int c = 0; c < 8; ++c) {
        __syncthreads();    // publishes buf[c&1]
        if (c < 7) stage_chunk(c + 1, WS + ((c + 1) & 1) * 16384, Cm, Bm, b, tid);
        const unsigned short* p = WS + (c & 1) * 16384;
        #pragma unroll
        for (int ks = 0; ks < 2; ++ks) {
            int kl = ks * 32 + quad * 8;
            bf16x8 ah  = *(const bf16x8*)(p +         swz_idx(mi * 16 + lm, kl));
            bf16x8 al  = *(const bf16x8*)(p +  4096 + swz_idx(mi * 16 + lm, kl));
            bf16x8 b0h = *(const bf16x8*)(p +  8192 + swz_idx(ni0 * 16 + lm, kl));
            bf16x8 b0l = *(const bf16x8*)(p + 12288 + swz_idx(ni0 * 16 + lm, kl));
            bf16x8 b1h = *(const bf16x8*)(p +  8192 + swz_idx((ni0 + 1) * 16 + lm, kl));
            bf16x8 b1l = *(const bf16x8*)(p + 12288 + swz_idx((ni0 + 1) * 16 + lm, kl));
            acc0 = __builtin_amdgcn_mfma_f32_16x16x32_bf16(ah, b0h, acc0, 0, 0, 0);
            acc0 = __builtin_amdgcn_mfma_f32_16x16x32_bf16(ah, b0l, acc0, 0, 0, 0);
            acc0 = __builtin_amdgcn_mfma_f32_16x16x32_bf16(al, b0h, acc0, 0, 0, 0);
            acc1 = __builtin_amdgcn_mfma_f32_16x16x32_bf16(ah, b1h, acc1, 0, 0, 0);
            acc1 = __builtin_amdgcn_mfma_f32_16x16x32_bf16(ah, b1l, acc1, 0, 0, 0);
            acc1 = __builtin_amdgcn_mfma_f32_16x16x32_bf16(al, b1h, acc1, 0, 0, 0);
        }
    }
    // C/D layout: col = lane&15, row = quad*4 + r
    #pragma unroll
    for (int r = 0; r < 4; ++r) {
        int row = mi * 16 + quad * 4 + r;
        CBsh[row * 64 + ni0 * 16 + lm] = f2bf(acc0[r]);
        CBsh[row * 64 + (ni0 + 1) * 16 + lm] = f2bf(acc1[r]);
    }
    __syncthreads();   // publishes CBsh + ecsh; stage buffers dead -> WS becomes Wl

    // ---- band normalize (wave-private; lane i = row i of own head's band) ----
    {
        float eci = ecsh[lane];
        #pragma unroll
        for (int s = 0; s < 7; ++s) {
            int src = lane - 1 - s;
            if (src >= 0) {
                float p = eci * ecsh[src];
                float f = fminf(1.f, rsqrtf(p));   // = 1/max(1,sqrt(p)); p=0 -> 1
                Ab[w][lane * 7 + s] *= f;
            }
        }
    }

    // ---- banded forward solve (all 8 waves, own head; software-pipelined) ----
    unsigned short* Wlw = WS + w * 4096;
    {
        const int j = lane;
        const float Dh = Dp[w];
        float mwin[7] = {0.f, 0.f, 0.f, 0.f, 0.f, 0.f, 0.f};
        float cab[7];
        #pragma unroll
        for (int s = 0; s < 7; ++s) cab[s] = Ab[w][s];
        float cbv = bf2f(CBsh[j]);
        float dnv = dnsh[w][0];
        for (int i = 0; i < 64; ++i) {
            float nab[7], ncb = 0.f, ndn = 0.f;
            if (i < 63) {
                #pragma unroll
                for (int s = 0; s < 7; ++s) nab[s] = Ab[w][(i + 1) * 7 + s];
                ncb = bf2f(CBsh[(i + 1) * 64 + j]);
                ndn = dnsh[w][i + 1];
            } else {
                #pragma unroll
                for (int s = 0; s < 7; ++s) nab[s] = 0.f;
            }
            float diag = (j == i) ? 1.f : 0.f;
            float t0 = fmaf(cab[0], mwin[0], fmaf(cab[1], mwin[1], diag));
            float t1 = fmaf(cab[2], mwin[2], fmaf(cab[3], mwin[3], cab[4] * mwin[4]));
            float t2 = fmaf(cab[5], mwin[5], cab[6] * mwin[6]);
            float mi_ = t0 + (t1 + t2);
            float wv = mi_ * cbv * dnv;
            if (j == i) wv += Dh;
            Wlw[swz_idx(i, j)] = f2bf(wv);   // i uniform -> conflict-free
            #pragma unroll
            for (int s = 6; s > 0; --s) mwin[s] = mwin[s - 1];
            mwin[0] = mi_;
            #pragma unroll
            for (int s = 0; s < 7; ++s) cab[s] = nab[s];
            cbv = ncb;
            dnv = ndn;
        }
    }

    // ---- y = W·X via mfma (wave-private); eb-inner stores for write merging ----
    {
        bf16x8 bf[4][2];
        #pragma unroll
        for (int eb = 0; eb < 4; ++eb) {
            int er = eb * 16 + lm;
            bf[eb][0] = *(const bf16x8*)(&Xt[w][swz_idx(er, quad * 8)]);
            bf[eb][1] = *(const bf16x8*)(&Xt[w][swz_idx(er, 32 + quad * 8)]);
        }
        float* og = out + (size_t)b * 64 * DIN + w * 64;
        #pragma unroll
        for (int m2 = 0; m2 < 4; ++m2) {
            int row0 = m2 * 16 + lm;
            bf16x8 a0 = *(const bf16x8*)(&Wlw[swz_idx(row0, quad * 8)]);
            bf16x8 a1 = *(const bf16x8*)(&Wlw[swz_idx(row0, 32 + quad * 8)]);
            f32x4 acc[4];
            #pragma unroll
            for (int eb = 0; eb < 4; ++eb) {
                f32x4 z = {0.f, 0.f, 0.f, 0.f};
                z = __builtin_amdgcn_mfma_f32_16x16x32_bf16(a0, bf[eb][0], z, 0, 0, 0);
                z = __builtin_amdgcn_mfma_f32_16x16x32_bf16(a1, bf[eb][1], z, 0, 0, 0);
                acc[eb] = z;
            }
            #pragma unroll
            for (int r = 0; r < 4; ++r) {
                int row = m2 * 16 + quad * 4 + r;
                #pragma unroll
                for (int eb = 0; eb < 4; ++eb)
                    og[(size_t)row * DIN + eb * 16 + lm] = acc[eb][r];
            }
        }
    }
}

extern "C" void kernel_launch(void* const* d_in, const int* in_sizes, int n_in,
                              void* d_out, int out_size, void* d_ws, size_t ws_size,
                              hipStream_t stream) {
    (void)in_sizes; (void)n_in; (void)out_size; (void)d_ws; (void)ws_size;
    dag_fused_v3<<<dim3(NGRAPH), dim3(512), 0, stream>>>(
        (const float*)d_in[0],   // x
        (const float*)d_in[1],   // B
        (const float*)d_in[2],   // C
        (const float*)d_in[3],   // dt
        (const float*)d_in[4],   // dt_edge
        (const float*)d_in[5],   // dt_bias
        (const float*)d_in[6],   // D
        (const float*)d_in[7],   // dag_masks
        (const int*)d_in[8],     // edge_index
        (float*)d_out);
}